// Round 14
// baseline (243.724 us; speedup 1.0000x reference)
//
#include <hip/hip_runtime.h>
#include <hip/hip_bf16.h>
#include <cstdint>
#include <cstddef>

#define S_LEN 2048
#define NH 12
#define HD 64
#define EDIM 768
// exponent = -(D_INTRINSIC + BETA) = -3.5, BANDWIDTH^0.5 = 1

typedef short bf16x8 __attribute__((ext_vector_type(8)));
typedef float f32x4  __attribute__((ext_vector_type(4)));
typedef float f32x2  __attribute__((ext_vector_type(2)));

__device__ __forceinline__ unsigned short f2bf(float f) {
    return __bfloat16_as_ushort(__float2bfloat16(f));
}
__device__ __forceinline__ float bf2f(unsigned short u) {
    union { unsigned int i; float f; } x;
    x.i = ((unsigned int)u) << 16;
    return x.f;
}
__device__ __forceinline__ float rsq_f32(float x) {
#if __has_builtin(__builtin_amdgcn_rsqf)
    return __builtin_amdgcn_rsqf(x);
#else
    return __builtin_amdgcn_rcpf(__builtin_amdgcn_sqrtf(x));
#endif
}

// 2-bit row-dependent chunk swizzle: LDS chunk c of row r holds global chunk
// c ^ swz4(r) (verified R10: absmax unchanged).  XOR = involution.
__device__ __forceinline__ int swz4(int r) { return (r + (r >> 2)) & 3; }

// async global->LDS, 16 B per lane; LDS dest is wave-uniform base + lane*16.
__device__ __forceinline__ void gload16(const unsigned short* g, unsigned short* l) {
    __builtin_amdgcn_global_load_lds(
        (const __attribute__((address_space(1))) unsigned int*)g,
        (__attribute__((address_space(3))) unsigned int*)l,
        16, 0, 0);
}

// ---------------------------------------------------------------------------
// Kernel 0: one-shot fp32 -> bf16 pre-cast of hs, Wq|Wv (concatenated), Wo.
// ---------------------------------------------------------------------------
__global__ __launch_bounds__(256) void precast_kernel(
    const float* __restrict__ hs, const float* __restrict__ Wq,
    const float* __restrict__ Wv, const float* __restrict__ Wo,
    unsigned short* __restrict__ hsb, unsigned short* __restrict__ Wqvb,
    unsigned short* __restrict__ Wob)
{
    const int i4 = blockIdx.x * 256 + threadIdx.x;   // 0..1228799
    const float* src;
    unsigned short* dst;
    int rel;
    if (i4 < 786432)        { src = hs; dst = hsb;            rel = i4; }
    else if (i4 < 933888)   { src = Wq; dst = Wqvb;           rel = i4 - 786432; }
    else if (i4 < 1081344)  { src = Wv; dst = Wqvb + 589824;  rel = i4 - 933888; }
    else                    { src = Wo; dst = Wob;            rel = i4 - 1081344; }
    float4 v = ((const float4*)src)[rel];
    ushort4 o;
    o.x = f2bf(v.x); o.y = f2bf(v.y); o.z = f2bf(v.z); o.w = f2bf(v.w);
    ((ushort4*)dst)[rel] = o;
}

// ---------------------------------------------------------------------------
// Kernel 1: Q/V projection, bf16 MFMA GEMM.  R10 config (best measured):
// 64x128 tiles, 4 waves (2x2), wave-tile 32x64, grid (12, 64) = 768 blocks.
// gload16 staging into linear LDS with swz4 source pre-swizzle, double-
// buffered, one __syncthreads per K-step.  LDS 24 KB.
// ---------------------------------------------------------------------------
__global__ __launch_bounds__(256) void qv_gemm(
    const unsigned short* __restrict__ hsb, const unsigned short* __restrict__ Wqvb,
    const float* __restrict__ bq, const float* __restrict__ bv,
    unsigned short* __restrict__ Qb, unsigned short* __restrict__ Vt,
    float* __restrict__ qn)
{
    __shared__ __align__(16) unsigned short As[2][64][32];    //  8 KB
    __shared__ __align__(16) unsigned short Bs[2][128][32];   // 16 KB

    const int t  = threadIdx.x;
    const int m0 = blockIdx.y << 6;
    const int c0 = blockIdx.x << 7;
    const bool isQ = (c0 < EDIM);
    const float* bias = isQ ? bq : bv;
    const int cb = isQ ? c0 : (c0 - EDIM);

    const int w  = t >> 6;
    const int l  = t & 63;
    const int ll = l & 15;
    const int lq = l >> 4;
    const int wx = w & 1;
    const int wy = w >> 1;

    const int arow  = (w << 4) + (l >> 2);
    const int brow0 = (w << 5) + (l >> 2);
    const int brow1 = brow0 + 16;
    const unsigned short* aSrc  = hsb  + (size_t)(m0 + arow ) * EDIM + (((l & 3) ^ swz4(arow )) << 3);
    const unsigned short* bSrc0 = Wqvb + (size_t)(c0 + brow0) * EDIM + (((l & 3) ^ swz4(brow0)) << 3);
    const unsigned short* bSrc1 = Wqvb + (size_t)(c0 + brow1) * EDIM + (((l & 3) ^ swz4(brow1)) << 3);

    f32x4 acc[2][4];
#pragma unroll
    for (int m = 0; m < 2; m++)
#pragma unroll
        for (int n = 0; n < 4; n++) acc[m][n] = (f32x4){0.f, 0.f, 0.f, 0.f};

    gload16(aSrc,  &As[0][w << 4][0]);
    gload16(bSrc0, &Bs[0][w << 5][0]);
    gload16(bSrc1, &Bs[0][(w << 5) + 16][0]);
    __syncthreads();

    int cur = 0;
    for (int k0 = 0; k0 < EDIM; k0 += 32) {
        if (k0 + 32 < EDIM) {
            gload16(aSrc  + k0 + 32, &As[cur ^ 1][w << 4][0]);
            gload16(bSrc0 + k0 + 32, &Bs[cur ^ 1][w << 5][0]);
            gload16(bSrc1 + k0 + 32, &Bs[cur ^ 1][(w << 5) + 16][0]);
        }
        bf16x8 aF[2], bF[4];
#pragma unroll
        for (int m = 0; m < 2; m++) {
            const int row = (wy << 5) + (m << 4) + ll;
            aF[m] = *(const bf16x8*)&As[cur][row][(lq ^ swz4(row)) << 3];
        }
#pragma unroll
        for (int n = 0; n < 4; n++) {
            const int row = (wx << 6) + (n << 4) + ll;
            bF[n] = *(const bf16x8*)&Bs[cur][row][(lq ^ swz4(row)) << 3];
        }
#pragma unroll
        for (int m = 0; m < 2; m++)
#pragma unroll
            for (int n = 0; n < 4; n++)
                acc[m][n] = __builtin_amdgcn_mfma_f32_16x16x32_bf16(aF[m], bF[n], acc[m][n], 0, 0, 0);
        __syncthreads();
        cur ^= 1;
    }

    const int hcol0 = cb + (wx << 6);
    const int h = hcol0 >> 6;
    const int rowbase = m0 + (wy << 5);
    const int b = rowbase >> 11;
    const int sbase = rowbase & 2047;

    if (isQ) {
#pragma unroll
        for (int m = 0; m < 2; m++) {
#pragma unroll
            for (int r = 0; r < 4; r++) {
                const int si = sbase + (m << 4) + (lq << 2) + r;
                unsigned short* qrow = Qb + ((size_t)(b * NH + h) * S_LEN + si) * HD;
                float qsq = 0.f;
#pragma unroll
                for (int n = 0; n < 4; n++) {
                    unsigned short u = f2bf(acc[m][n][r] + bias[hcol0 + (n << 4) + ll]);
                    qrow[(n << 4) + ll] = u;
                    float f = bf2f(u);
                    qsq += f * f;
                }
                qsq += __shfl_xor(qsq, 1);
                qsq += __shfl_xor(qsq, 2);
                qsq += __shfl_xor(qsq, 4);
                qsq += __shfl_xor(qsq, 8);
                if (ll == 0) qn[(b * NH + h) * S_LEN + si] = qsq;
            }
        }
    } else {
#pragma unroll
        for (int m = 0; m < 2; m++) {
            const int si = sbase + (m << 4) + (lq << 2);
#pragma unroll
            for (int n = 0; n < 4; n++) {
                ushort4 o;
                o.x = f2bf(acc[m][n][0] + bias[hcol0 + (n << 4) + ll]);
                o.y = f2bf(acc[m][n][1] + bias[hcol0 + (n << 4) + ll]);
                o.z = f2bf(acc[m][n][2] + bias[hcol0 + (n << 4) + ll]);
                o.w = f2bf(acc[m][n][3] + bias[hcol0 + (n << 4) + ll]);
                *(ushort4*)&Vt[((size_t)(b * NH + h) * HD + (n << 4) + ll) * S_LEN + si] = o;
            }
        }
    }
}

// ---------------------------------------------------------------------------
// attn tile step.  R14: V double-buffer moved from VGPRs to wave-private
// lane-linear LDS (Vs[buf][m][64][8]) via gload16 -> frees ~32 arch regs
// so 3 waves/SIMD fit WITH the full-step V latency slack (R7 lost depth,
// R8 spilled; this keeps both).  PV reads V frags back with ds_read_b128
// at lane-linear addresses (conflict-free).  All else = R6 structure.
// ---------------------------------------------------------------------------
template<int CUR>
__device__ __forceinline__ void attn_tile32(
    int j0, int jn,
    const unsigned short* __restrict__ Qbase,
    const unsigned short* __restrict__ Vbase,
    const float* __restrict__ qnb, const float* __restrict__ mb,
    int l, int ll, int lq,
    const bf16x8 (&aQ)[2][2],
    const f32x2 (&qni2)[2][2], const f32x2 (&keepi2)[2][2],
    const bf16x8& ones,
    f32x4 (&oacc)[2][4], f32x4 (&wacc)[2],
    bf16x8 (&nb0)[2], bf16x8 (&nb1)[2],
    unsigned short (&Vs)[2][4][64][8],
    float (&qnjv)[2][2], float (&kjm)[2][2],
    unsigned short (&Wt)[2][2][16][40])
{
    constexpr int PRV = CUR ^ 1;
    __builtin_amdgcn_wave_barrier();   // strip[PRV] writes (prev tile) before reads below
    // V-frags for current tile -> LDS (consumed next tile); lane l's 16B
    // lands at Vs[CUR][m] + l*16 (hardware lane offset).
#pragma unroll
    for (int m = 0; m < 4; m++)
        gload16(Vbase + (size_t)((m << 4) + ll) * S_LEN + j0 + (lq << 3),
                &Vs[CUR][m][0][0]);
    // ---- gram(j0) with prefetched B-frags
    f32x4 s[2][2];
#pragma unroll
    for (int s2 = 0; s2 < 2; s2++)
#pragma unroll
        for (int n = 0; n < 2; n++) {
            f32x4 c = (f32x4){0.f, 0.f, 0.f, 0.f};
            c = __builtin_amdgcn_mfma_f32_16x16x32_bf16(aQ[s2][0], nb0[n], c, 0, 0, 0);
            c = __builtin_amdgcn_mfma_f32_16x16x32_bf16(aQ[s2][1], nb1[n], c, 0, 0, 0);
            s[s2][n] = c;
        }
    // ---- prefetch B-frags + qn/mask (next tile)
#pragma unroll
    for (int n = 0; n < 2; n++) {
        const unsigned short* bp = Qbase + (size_t)(jn + (n << 4) + ll) * HD + (lq << 3);
        nb0[n] = *(const bf16x8*)bp;
        nb1[n] = *(const bf16x8*)(bp + 32);
        int jc = jn + (n << 4) + ll;
        qnjv[PRV][n] = qnb[jc];
        kjm[PRV][n]  = (mb[jc] >= 0.f) ? 1.f : 0.f;
    }
    // ---- PV(previous tile): V frags from LDS (written a full step ago)
#pragma unroll
    for (int s2 = 0; s2 < 2; s2++) {
        bf16x8 aP = *(const bf16x8*)&Wt[PRV][s2][ll][lq << 3];
#pragma unroll
        for (int m = 0; m < 4; m++) {
            bf16x8 vf = *(const bf16x8*)&Vs[PRV][m][l][0];
            oacc[s2][m] = __builtin_amdgcn_mfma_f32_16x16x32_bf16(aP, vf, oacc[s2][m], 0, 0, 0);
        }
        wacc[s2] = __builtin_amdgcn_mfma_f32_16x16x32_bf16(aP, ones, wacc[s2], 0, 0, 0);
    }
    // ---- transform(current) -> strip[CUR], packed f32 pairs over r
#pragma unroll
    for (int s2 = 0; s2 < 2; s2++)
#pragma unroll
        for (int n = 0; n < 2; n++) {
            const f32x2 qv = (f32x2)(qnjv[CUR][n]);
            const f32x2 kj = (f32x2)(kjm[CUR][n]);
#pragma unroll
            for (int pr = 0; pr < 2; pr++) {
                f32x2 sp = { s[s2][n][2*pr], s[s2][n][2*pr + 1] };
                f32x2 d2 = __builtin_elementwise_fma(sp, (f32x2)(-2.f), qni2[s2][pr] + qv);
                d2 = __builtin_elementwise_max(d2, (f32x2)(1e-12f));
                f32x2 dist = { __builtin_amdgcn_sqrtf(d2.x), __builtin_amdgcn_sqrtf(d2.y) };
                f32x2 km = keepi2[s2][pr] * kj;
                f32x2 x  = __builtin_elementwise_fma(km, dist + (f32x2)(-2.f), (f32x2)(3.f));
                f32x2 x2 = x * x;
                f32x2 x4 = x2 * x2;
                f32x2 x6 = x4 * x2;
                f32x2 x7 = x6 * x;
                f32x2 p  = { rsq_f32(x7.x), rsq_f32(x7.y) };   // (1+d)^-3.5
                f32x2 wv = __builtin_elementwise_fma(
                    __builtin_elementwise_fma(
                        __builtin_elementwise_fma(
                            __builtin_elementwise_fma((f32x2)(0.041666668f), p, (f32x2)(0.16666667f)),
                            p, (f32x2)(0.5f)),
                        p, (f32x2)(1.0f)),
                    p, (f32x2)(1.0f));
                union { float f; unsigned int u; } c0, c1;
                c0.f = wv.x; c1.f = wv.y;
                Wt[CUR][s2][(lq << 2) + 2*pr    ][(n << 4) + ll] = (unsigned short)((c0.u + 0x8000u) >> 16);
                Wt[CUR][s2][(lq << 2) + 2*pr + 1][(n << 4) + ll] = (unsigned short)((c1.u + 0x8000u) >> 16);
            }
        }
}

// ---------------------------------------------------------------------------
// Kernel 2: MFMA distance attention.  R14 = R6 structure with V staged in
// LDS (gload16, wave-private, double-buffered) instead of VGPRs: ~156-164
// total regs -> 3 waves/SIMD with full pipeline depth.  LDS 53248 B/block
// (Wt 20480 + Vs 32768) -> exactly 3 blocks/CU.  NO clamp, NO setprio.
// Cross-wave reduction: 3-stage LDS tree aliasing Wt.  Grid id = ib*24+bh.
// ---------------------------------------------------------------------------
__global__ __launch_bounds__(256) void attn_kernel(
    const unsigned short* __restrict__ Qb, const unsigned short* __restrict__ Vt,
    const float* __restrict__ qn, const float* __restrict__ mask,
    unsigned short* __restrict__ AObf)
{
    __shared__ __align__(16) unsigned short Wt[4][2][2][16][40];   // 20480 B
    __shared__ __align__(16) unsigned short Vs[4][2][4][64][8];    // 32768 B

    const int t  = threadIdx.x;
    const int w  = t >> 6;                     // wave id 0..3
    const int l  = t & 63;
    const int ll = l & 15;
    const int lq = l >> 4;
    const int id = blockIdx.x;
    const int ib = id / 24;
    const int bh = id - ib * 24;
    const int b  = bh / NH;
    const int h  = bh - b * NH;
    const int iw = ib << 5;                    // 32 i-rows (shared by all 4 waves)

    const unsigned short* Qbase = Qb + ((size_t)bh << 17);
    const unsigned short* Vbase = Vt + ((size_t)bh << 17);
    const float* qnb = qn + (bh << 11);
    const float* mb  = mask + (b << 11);

    unsigned short (&Wtw)[2][2][16][40] = Wt[w];
    unsigned short (&Vsw)[2][4][64][8]  = Vs[w];

    // this wave's j-chunk: tiles [tbase, tbase+16), j in [jb, jb+512)
    const int tbase = w << 4;
    const int jb    = tbase << 5;

    // A-frags for both 16-row sub-tiles, held all loop
    bf16x8 aQ[2][2];
#pragma unroll
    for (int s2 = 0; s2 < 2; s2++) {
        const unsigned short* qp = Qbase + (size_t)(iw + (s2 << 4) + ll) * HD + (lq << 3);
        aQ[s2][0] = *(const bf16x8*)qp;
        aQ[s2][1] = *(const bf16x8*)(qp + 32);
    }

    f32x2 qni2[2][2], keepi2[2][2];
#pragma unroll
    for (int s2 = 0; s2 < 2; s2++)
#pragma unroll
        for (int pr = 0; pr < 2; pr++) {
            int r0 = iw + (s2 << 4) + (lq << 2) + 2*pr;
            qni2[s2][pr]   = (f32x2){ qnb[r0], qnb[r0 + 1] };
            keepi2[s2][pr] = (f32x2){ (mb[r0] >= 0.f) ? 1.f : 0.f,
                                      (mb[r0 + 1] >= 0.f) ? 1.f : 0.f };
        }

    bf16x8 ones;
#pragma unroll
    for (int i = 0; i < 8; i++) ones[i] = (short)0x3F80;   // bf16 1.0

    f32x4 oacc[2][4];
#pragma unroll
    for (int s2 = 0; s2 < 2; s2++)
#pragma unroll
        for (int m = 0; m < 4; m++) oacc[s2][m] = (f32x4){0.f, 0.f, 0.f, 0.f};
    f32x4 wacc[2];
    wacc[0] = (f32x4){0.f, 0.f, 0.f, 0.f};
    wacc[1] = (f32x4){0.f, 0.f, 0.f, 0.f};

    // gram B-frags + qn/mask for first tile of chunk
    bf16x8 nb0[2], nb1[2];
    float qnjv[2][2], kjm[2][2];
#pragma unroll
    for (int n = 0; n < 2; n++) {
        const unsigned short* bp = Qbase + (size_t)(jb + (n << 4) + ll) * HD + (lq << 3);
        nb0[n] = *(const bf16x8*)bp;
        nb1[n] = *(const bf16x8*)(bp + 32);
        int jc = jb + (n << 4) + ll;
        qnjv[0][n] = qnb[jc];
        kjm[0][n]  = (mb[jc] >= 0.f) ? 1.f : 0.f;
    }

    // ---- peeled tile tbase: V -> Vs[0], scores -> strip[0],
    //      prefetch B/qn/mask for tile tbase+1
    {
#pragma unroll
        for (int m = 0; m < 4; m++)
            gload16(Vbase + (size_t)((m << 4) + ll) * S_LEN + jb + (lq << 3),
                    &Vsw[0][m][0][0]);
        f32x4 s[2][2];
#pragma unroll
        for (int s2 = 0; s2 < 2; s2++)
#pragma unroll
            for (int n = 0; n < 2; n++) {
                f32x4 c = (f32x4){0.f, 0.f, 0.f, 0.f};
                c = __builtin_amdgcn_mfma_f32_16x16x32_bf16(aQ[s2][0], nb0[n], c, 0, 0, 0);
                c = __builtin_amdgcn_mfma_f32_16x16x32_bf16(aQ[s2][1], nb1[n], c, 0, 0, 0);
                s[s2][n] = c;
            }
#pragma unroll
        for (int n = 0; n < 2; n++) {
            const unsigned short* bp = Qbase + (size_t)(jb + 32 + (n << 4) + ll) * HD + (lq << 3);
            nb0[n] = *(const bf16x8*)bp;
            nb1[n] = *(const bf16x8*)(bp + 32);
            int jc = jb + 32 + (n << 4) + ll;
            qnjv[1][n] = qnb[jc];
            kjm[1][n]  = (mb[jc] >= 0.f) ? 1.f : 0.f;
        }
#pragma unroll
        for (int s2 = 0; s2 < 2; s2++)
#pragma unroll
            for (int n = 0; n < 2; n++) {
                const f32x2 qv = (f32x2)(qnjv[0][n]);
                const f32x2 kj = (f32x2)(kjm[0][n]);
#pragma unroll
                for (int pr = 0; pr < 2; pr++) {
                    f32x2 sp = { s[s2][n][2*pr], s[s2][n][2*pr + 1] };
                    f32x2 d2 = __builtin_elementwise_fma(sp, (f32x2)(-2.f), qni2[s2][pr] + qv);
                    d2 = __builtin_elementwise_max(d2, (f32x2)(1e-12f));
                    f32x2 dist = { __builtin_amdgcn_sqrtf(d2.x), __builtin_amdgcn_sqrtf(d2.y) };
                    f32x2 km = keepi2[s2][pr] * kj;
                    f32x2 x  = __builtin_elementwise_fma(km, dist + (f32x2)(-2.f), (f32x2)(3.f));
                    f32x2 x2 = x * x;
                    f32x2 x4 = x2 * x2;
                    f32x2 x6 = x4 * x2;
                    f32x2 x7 = x6 * x;
                    f32x2 p  = { rsq_f32(x7.x), rsq_f32(x7.y) };
                    f32x2 wv = __builtin_elementwise_fma(
                        __builtin_elementwise_fma(
                            __builtin_elementwise_fma(
                                __builtin_elementwise_fma((f32x2)(0.041666668f), p, (f32x2)(0.16666667f)),
                                p, (f32x2)(0.5f)),
                            p, (f32x2)(1.0f)),
                        p, (f32x2)(1.0f));
                    union { float f; unsigned int u; } c0, c1;
                    c0.f = wv.x; c1.f = wv.y;
                    Wtw[0][s2][(lq << 2) + 2*pr    ][(n << 4) + ll] = (unsigned short)((c0.u + 0x8000u) >> 16);
                    Wtw[0][s2][(lq << 2) + 2*pr + 1][(n << 4) + ll] = (unsigned short)((c1.u + 0x8000u) >> 16);
                }
            }
    }

    // ---- tiles tbase+1 .. tbase+14 as 7 template-unrolled pairs
    //      (odd tile CUR=1, even tile CUR=0)
    for (int tt = tbase + 1; tt <= tbase + 13; tt += 2) {
        attn_tile32<1>(tt << 5, (tt + 1) << 5, Qbase, Vbase, qnb, mb, l, ll, lq,
                       aQ, qni2, keepi2, ones, oacc, wacc, nb0, nb1, Vsw, qnjv, kjm, Wtw);
        attn_tile32<0>((tt + 1) << 5, (tt + 2) << 5, Qbase, Vbase, qnb, mb, l, ll, lq,
                       aQ, qni2, keepi2, ones, oacc, wacc, nb0, nb1, Vsw, qnjv, kjm, Wtw);
    }
    // ---- tile tbase+15 (CUR=1; next-prefetch wraps to j=0, harmless)
    attn_tile32<1>((tbase + 15) << 5, 0, Qbase, Vbase, qnb, mb, l, ll, lq,
                   aQ, qni2, keepi2, ones, oacc, wacc, nb0, nb1, Vsw, qnjv, kjm, Wtw);

    // ---- drain: PV(last tile) from strip[1]/Vs[1]
    __builtin_amdgcn_wave_barrier();
#pragma unroll
    for (int s2 = 0; s2 < 2; s2++) {
        bf16x8 aP = *(const bf16x8*)&Wtw[1][s2][ll][lq << 3];
#pragma unroll
        for (int m = 0; m < 4; m++) {
            bf16x8 vf = *(const bf16x8*)&Vsw[1][m][l][0];
            oacc[s2][m] = __builtin_amdgcn_mfma_f32_16x16x32_bf16(aP, vf, oacc[s2][m], 0, 0, 0);
        }
        wacc[s2] = __builtin_amdgcn_mfma_f32_16x16x32_bf16(aP, ones, wacc[s2], 0, 0, 0);
    }

    // ---- cross-wave reduction of partials (40 f32/lane), LDS aliases Wt.
    //      Layout lane-major: red[slot*128 + idx], conflict-free.
    float* red = (float*)Wt;
    __syncthreads();
    if (w >= 2) {
        float* p = red + (((w - 2) << 6) + l);
#pragma unroll
        for (int s2 = 0; s2 < 2; s2++)
#pragma unroll
            for (int m = 0; m < 4; m++)
#pragma unroll
                for (int r = 0; r < 4; r++)
                    p[((((s2 << 2) + m) << 2) + r) * 128] = oacc[s2][m][r];
#pragma unroll
        for (int s2 = 0; s2 < 2; s2++)
#pragma unroll
            for (int r = 0; r < 4; r++)
                p[(32 + (s2 << 2) + r) * 128] = wacc[s2][r];
    }
    __syncthreads();
    if (w < 2) {
        float* p = red + ((w << 6) + l);
#pragma unroll
        for (int s2 = 0; s2 < 2; s2++)
#pragma unroll
            for (int m = 0; m < 4; m++)
#pragma unroll
                for (int r = 0; r < 4; r++)
                    oacc[s2][m][r] += p[((((s2 << 2) + m) << 2) + r) * 128];
#pragma unroll
        for (int s2 = 0; s2 < 2; s2++)
#pragma unroll
            for (int r = 0; r < 4; r++)
                wacc[s2][r] += p[(32 + (s2 << 2) + r) * 128];
    }
    __syncthreads();
    if (w == 1) {
        float* p = red + l;
#pragma unroll
        for (int s2 = 0; s2 < 2; s2++)
#pragma unroll
            for (int m = 0; m < 4; m++)
#pragma unroll
                for (int r = 0; r < 4; r++)
                    p[((((s2 << 2) + m) << 2) + r) * 128] = oacc[s2][m][r];
#pragma unroll
        for (int s2 = 0; s2 < 2; s2++)
#pragma unroll
            for (int r = 0; r < 4; r++)
                p[(32 + (s2 << 2) + r) * 128] = wacc[s2][r];
    }
    __syncthreads();
    if (w == 0) {
        float* p = red + l;
#pragma unroll
        for (int s2 = 0; s2 < 2; s2++)
#pragma unroll
            for (int m = 0; m < 4; m++)
#pragma unroll
                for (int r = 0; r < 4; r++)
                    oacc[s2][m][r] += p[((((s2 << 2) + m) << 2) + r) * 128];
#pragma unroll
        for (int s2 = 0; s2 < 2; s2++)
#pragma unroll
            for (int r = 0; r < 4; r++)
                wacc[s2][r] += p[(32 + (s2 << 2) + r) * 128];

        // ---- epilogue (wave 0 holds full sums): normalize + store 32 rows
#pragma unroll
        for (int s2 = 0; s2 < 2; s2++)
#pragma unroll
            for (int r = 0; r < 4; r++) {
                float inv = 1.0f / wacc[s2][r];
                const int row = iw + (s2 << 4) + (lq << 2) + r;
                unsigned short* dst = AObf + (size_t)((b << 11) + row) * EDIM + (h << 6);
#pragma unroll
                for (int m = 0; m < 4; m++)
                    dst[(m << 4) + ll] = f2bf(oacc[s2][m][r] * inv);
            }
    }
}

// ---------------------------------------------------------------------------
// Kernel 3a: out-projection bf16 MFMA GEMM + bias + residual (fp32 out).
// R10 config (best measured): 64x64 tiles, grid (12, 64), gload16 + swz4
// staging, double-buffered.  LDS 16 KB.
// ---------------------------------------------------------------------------
__global__ __launch_bounds__(256) void oproj_gemm(
    const unsigned short* __restrict__ AObf, const unsigned short* __restrict__ Wob,
    const float* __restrict__ bo, const float* __restrict__ hs,
    float* __restrict__ TMP)
{
    __shared__ __align__(16) unsigned short As[2][64][32];
    __shared__ __align__(16) unsigned short Bs[2][64][32];

    const int t  = threadIdx.x;
    const int m0 = blockIdx.y << 6;
    const int c0 = blockIdx.x << 6;

    const int w  = t >> 6;
    const int l  = t & 63;
    const int ll = l & 15;
    const int lq = l >> 4;
    const int wx = w & 1;
    const int wy = w >> 1;

    const int srow = (w << 4) + (l >> 2);
    const unsigned short* aSrc = AObf + (size_t)(m0 + srow) * EDIM + (((l & 3) ^ swz4(srow)) << 3);
    const unsigned short* bSrc = Wob  + (size_t)(c0 + srow) * EDIM + (((l & 3) ^ swz4(srow)) << 3);

    f32x4 acc[2][2];
#pragma unroll
    for (int m = 0; m < 2; m++)
#pragma unroll
        for (int n = 0; n < 2; n++) acc[m][n] = (f32x4){0.f, 0.f, 0.f, 0.f};

    gload16(aSrc, &As[0][w << 4][0]);
    gload16(bSrc, &Bs[0][w << 4][0]);
    __syncthreads();

    int cur = 0;
    for (int k0 = 0; k0 < EDIM; k0 += 32) {
        if (k0 + 32 < EDIM) {
            gload16(aSrc + k0 + 32, &As[cur ^ 1][w << 4][0]);
            gload16(bSrc + k0 + 32, &Bs[cur ^ 1][w << 4][0]);
        }
        bf16x8 aF[2], bF[2];
#pragma unroll
        for (int m = 0; m < 2; m++) {
            const int row = (wy << 5) + (m << 4) + ll;
            aF[m] = *(const bf16x8*)&As[cur][row][(lq ^ swz4(row)) << 3];
        }
#pragma unroll
        for (int n = 0; n < 2; n++) {
            const int row = (wx << 5) + (n << 4) + ll;
            bF[n] = *(const bf16x8*)&Bs[cur][row][(lq ^ swz4(row)) << 3];
        }
#pragma unroll
        for (int m = 0; m < 2; m++)
#pragma unroll
            for (int n = 0; n < 2; n++)
                acc[m][n] = __builtin_amdgcn_mfma_f32_16x16x32_bf16(aF[m], bF[n], acc[m][n], 0, 0, 0);
        __syncthreads();
        cur ^= 1;
    }

#pragma unroll
    for (int m = 0; m < 2; m++) {
#pragma unroll
        for (int r = 0; r < 4; r++) {
            const int row = m0 + (wy << 5) + (m << 4) + (lq << 2) + r;
#pragma unroll
            for (int n = 0; n < 2; n++) {
                const int col = c0 + (wx << 5) + (n << 4) + ll;
                TMP[(size_t)row * EDIM + col] =
                    acc[m][n][r] + bo[col] + hs[(size_t)row * EDIM + col];
            }
        }
    }
}

// ---------------------------------------------------------------------------
// Kernel 3b: LayerNorm -> f32 output.  grid 4096, block 256.
// ---------------------------------------------------------------------------
__global__ __launch_bounds__(256) void ln_kernel(
    const float* __restrict__ X, const float* __restrict__ g,
    const float* __restrict__ be, float* __restrict__ out)
{
    const int row = blockIdx.x;
    const int t = threadIdx.x;
    const float* x = X + (size_t)row * EDIM;

    float s = 0.f, sq = 0.f;
#pragma unroll
    for (int c = t; c < EDIM; c += 256) {
        float v = x[c];
        s += v; sq += v * v;
    }
#pragma unroll
    for (int m = 1; m < 64; m <<= 1) {
        s  += __shfl_xor(s, m);
        sq += __shfl_xor(sq, m);
    }
    __shared__ float ss[4], ssq[4];
    const int w = t >> 6;
    if ((t & 63) == 0) { ss[w] = s; ssq[w] = sq; }
    __syncthreads();
    s  = ss[0] + ss[1] + ss[2] + ss[3];
    sq = ssq[0] + ssq[1] + ssq[2] + ssq[3];
    const float mu  = s * (1.f / EDIM);
    const float var = sq * (1.f / EDIM) - mu * mu;
    const float rstd = 1.0f / sqrtf(var + 1e-12f);

#pragma unroll
    for (int c = t; c < EDIM; c += 256) {
        out[(size_t)row * EDIM + c] = (x[c] - mu) * rstd * g[c] + be[c];
    }
}

// ---------------------------------------------------------------------------
extern "C" void kernel_launch(void* const* d_in, const int* in_sizes, int n_in,
                              void* d_out, int out_size, void* d_ws, size_t ws_size,
                              hipStream_t stream) {
    const float* hs   = (const float*)d_in[0];
    const float* mask = (const float*)d_in[1];
    const float* Wq   = (const float*)d_in[2];
    const float* bq   = (const float*)d_in[3];
    const float* Wv   = (const float*)d_in[4];
    const float* bv   = (const float*)d_in[5];
    const float* Wo   = (const float*)d_in[6];
    const float* bo   = (const float*)d_in[7];
    const float* g    = (const float*)d_in[8];
    const float* be   = (const float*)d_in[9];

    char* w8 = (char*)d_ws;
    unsigned short* Qb   = (unsigned short*)(w8);               //  6,291,456 B
    unsigned short* Vt   = (unsigned short*)(w8 +  6291456);    //  6,291,456 B
    float*          qn   = (float*)        (w8 + 12582912);     //    196,608 B
    unsigned short* AObf = (unsigned short*)(w8 + 12779520);    //  6,291,456 B
    unsigned short* hsb  = (unsigned short*)(w8 + 19070976);    //  6,291,456 B
    unsigned short* Wqvb = (unsigned short*)(w8 + 25362432);    //  2,359,296 B
    unsigned short* Wob  = (unsigned short*)(w8 + 27721728);    //  1,179,648 B
    float*          TMP  = (float*)(w8);                        // alias Qb+Vt (dead)

    precast_kernel<<<dim3(4800),    256, 0, stream>>>(hs, Wq, Wv, Wo, hsb, Wqvb, Wob);
    qv_gemm       <<<dim3(12, 64),  256, 0, stream>>>(hsb, Wqvb, bq, bv, Qb, Vt, qn);
    attn_kernel   <<<dim3(1536),    256, 0, stream>>>(Qb, Vt, qn, mask, AObf);
    oproj_gemm    <<<dim3(12, 64),  256, 0, stream>>>(AObf, Wob, bo, hs, TMP);
    ln_kernel     <<<dim3(4096),    256, 0, stream>>>(TMP, g, be, (float*)d_out);
}

// Round 15
// 231.803 us; speedup vs baseline: 1.0514x; 1.0514x over previous
//
#include <hip/hip_runtime.h>
#include <hip/hip_bf16.h>
#include <cstdint>
#include <cstddef>

#define S_LEN 2048
#define NH 12
#define HD 64
#define EDIM 768
// exponent = -(D_INTRINSIC + BETA) = -3.5, BANDWIDTH^0.5 = 1

typedef short bf16x8 __attribute__((ext_vector_type(8)));
typedef float f32x4  __attribute__((ext_vector_type(4)));
typedef float f32x2  __attribute__((ext_vector_type(2)));

__device__ __forceinline__ unsigned short f2bf(float f) {
    return __bfloat16_as_ushort(__float2bfloat16(f));
}
__device__ __forceinline__ float bf2f(unsigned short u) {
    union { unsigned int i; float f; } x;
    x.i = ((unsigned int)u) << 16;
    return x.f;
}
__device__ __forceinline__ float rsq_f32(float x) {
#if __has_builtin(__builtin_amdgcn_rsqf)
    return __builtin_amdgcn_rsqf(x);
#else
    return __builtin_amdgcn_rcpf(__builtin_amdgcn_sqrtf(x));
#endif
}

// 2-bit row-dependent chunk swizzle: LDS chunk c of row r holds global chunk
// c ^ swz4(r) (verified R10: absmax unchanged).  XOR = involution.
__device__ __forceinline__ int swz4(int r) { return (r + (r >> 2)) & 3; }

// async global->LDS, 16 B per lane; LDS dest is wave-uniform base + lane*16.
__device__ __forceinline__ void gload16(const unsigned short* g, unsigned short* l) {
    __builtin_amdgcn_global_load_lds(
        (const __attribute__((address_space(1))) unsigned int*)g,
        (__attribute__((address_space(3))) unsigned int*)l,
        16, 0, 0);
}

// ---------------------------------------------------------------------------
// Kernel 0: one-shot fp32 -> bf16 pre-cast of hs, Wq|Wv (concatenated), Wo.
// ---------------------------------------------------------------------------
__global__ __launch_bounds__(256) void precast_kernel(
    const float* __restrict__ hs, const float* __restrict__ Wq,
    const float* __restrict__ Wv, const float* __restrict__ Wo,
    unsigned short* __restrict__ hsb, unsigned short* __restrict__ Wqvb,
    unsigned short* __restrict__ Wob)
{
    const int i4 = blockIdx.x * 256 + threadIdx.x;   // 0..1228799
    const float* src;
    unsigned short* dst;
    int rel;
    if (i4 < 786432)        { src = hs; dst = hsb;            rel = i4; }
    else if (i4 < 933888)   { src = Wq; dst = Wqvb;           rel = i4 - 786432; }
    else if (i4 < 1081344)  { src = Wv; dst = Wqvb + 589824;  rel = i4 - 933888; }
    else                    { src = Wo; dst = Wob;            rel = i4 - 1081344; }
    float4 v = ((const float4*)src)[rel];
    ushort4 o;
    o.x = f2bf(v.x); o.y = f2bf(v.y); o.z = f2bf(v.z); o.w = f2bf(v.w);
    ((ushort4*)dst)[rel] = o;
}

// ---------------------------------------------------------------------------
// Kernel 1: Q/V projection, bf16 MFMA GEMM.  R10/R13 config (best measured):
// 64x128 tiles, 4 waves (2x2), wave-tile 32x64, grid (12, 64) = 768 blocks
// (exactly 3/CU).  gload16 width-16 staging into linear LDS with swz4
// source pre-swizzle, double-buffered, one __syncthreads per K-step.
// LDS 24 KB.  Epilogue: Q -> Qb bf16 [bh][s][64] + qn fp32; V -> Vt.
// ---------------------------------------------------------------------------
__global__ __launch_bounds__(256) void qv_gemm(
    const unsigned short* __restrict__ hsb, const unsigned short* __restrict__ Wqvb,
    const float* __restrict__ bq, const float* __restrict__ bv,
    unsigned short* __restrict__ Qb, unsigned short* __restrict__ Vt,
    float* __restrict__ qn)
{
    __shared__ __align__(16) unsigned short As[2][64][32];    //  8 KB
    __shared__ __align__(16) unsigned short Bs[2][128][32];   // 16 KB

    const int t  = threadIdx.x;
    const int m0 = blockIdx.y << 6;
    const int c0 = blockIdx.x << 7;
    const bool isQ = (c0 < EDIM);
    const float* bias = isQ ? bq : bv;
    const int cb = isQ ? c0 : (c0 - EDIM);

    const int w  = t >> 6;
    const int l  = t & 63;
    const int ll = l & 15;
    const int lq = l >> 4;
    const int wx = w & 1;
    const int wy = w >> 1;

    const int arow  = (w << 4) + (l >> 2);            // A rows 0..63
    const int brow0 = (w << 5) + (l >> 2);            // B rows w*32..+15
    const int brow1 = brow0 + 16;                     // B rows w*32+16..+31
    const unsigned short* aSrc  = hsb  + (size_t)(m0 + arow ) * EDIM + (((l & 3) ^ swz4(arow )) << 3);
    const unsigned short* bSrc0 = Wqvb + (size_t)(c0 + brow0) * EDIM + (((l & 3) ^ swz4(brow0)) << 3);
    const unsigned short* bSrc1 = Wqvb + (size_t)(c0 + brow1) * EDIM + (((l & 3) ^ swz4(brow1)) << 3);

    f32x4 acc[2][4];
#pragma unroll
    for (int m = 0; m < 2; m++)
#pragma unroll
        for (int n = 0; n < 4; n++) acc[m][n] = (f32x4){0.f, 0.f, 0.f, 0.f};

    // prologue: stage K-tile 0 into buffer 0
    gload16(aSrc,  &As[0][w << 4][0]);
    gload16(bSrc0, &Bs[0][w << 5][0]);
    gload16(bSrc1, &Bs[0][(w << 5) + 16][0]);
    __syncthreads();

    int cur = 0;
    for (int k0 = 0; k0 < EDIM; k0 += 32) {
        if (k0 + 32 < EDIM) {
            gload16(aSrc  + k0 + 32, &As[cur ^ 1][w << 4][0]);
            gload16(bSrc0 + k0 + 32, &Bs[cur ^ 1][w << 5][0]);
            gload16(bSrc1 + k0 + 32, &Bs[cur ^ 1][(w << 5) + 16][0]);
        }
        bf16x8 aF[2], bF[4];
#pragma unroll
        for (int m = 0; m < 2; m++) {
            const int row = (wy << 5) + (m << 4) + ll;
            aF[m] = *(const bf16x8*)&As[cur][row][(lq ^ swz4(row)) << 3];
        }
#pragma unroll
        for (int n = 0; n < 4; n++) {
            const int row = (wx << 6) + (n << 4) + ll;
            bF[n] = *(const bf16x8*)&Bs[cur][row][(lq ^ swz4(row)) << 3];
        }
#pragma unroll
        for (int m = 0; m < 2; m++)
#pragma unroll
            for (int n = 0; n < 4; n++)
                acc[m][n] = __builtin_amdgcn_mfma_f32_16x16x32_bf16(aF[m], bF[n], acc[m][n], 0, 0, 0);
        __syncthreads();   // drains vmcnt: next buffer complete; cur free to overwrite
        cur ^= 1;
    }

    const int hcol0 = cb + (wx << 6);        // head-aligned
    const int h = hcol0 >> 6;
    const int rowbase = m0 + (wy << 5);
    const int b = rowbase >> 11;
    const int sbase = rowbase & 2047;

    if (isQ) {
#pragma unroll
        for (int m = 0; m < 2; m++) {
#pragma unroll
            for (int r = 0; r < 4; r++) {
                const int si = sbase + (m << 4) + (lq << 2) + r;
                unsigned short* qrow = Qb + ((size_t)(b * NH + h) * S_LEN + si) * HD;
                float qsq = 0.f;
#pragma unroll
                for (int n = 0; n < 4; n++) {
                    unsigned short u = f2bf(acc[m][n][r] + bias[hcol0 + (n << 4) + ll]);
                    qrow[(n << 4) + ll] = u;
                    float f = bf2f(u);
                    qsq += f * f;
                }
                qsq += __shfl_xor(qsq, 1);
                qsq += __shfl_xor(qsq, 2);
                qsq += __shfl_xor(qsq, 4);
                qsq += __shfl_xor(qsq, 8);
                if (ll == 0) qn[(b * NH + h) * S_LEN + si] = qsq;
            }
        }
    } else {
#pragma unroll
        for (int m = 0; m < 2; m++) {
            const int si = sbase + (m << 4) + (lq << 2);
#pragma unroll
            for (int n = 0; n < 4; n++) {
                ushort4 o;
                o.x = f2bf(acc[m][n][0] + bias[hcol0 + (n << 4) + ll]);
                o.y = f2bf(acc[m][n][1] + bias[hcol0 + (n << 4) + ll]);
                o.z = f2bf(acc[m][n][2] + bias[hcol0 + (n << 4) + ll]);
                o.w = f2bf(acc[m][n][3] + bias[hcol0 + (n << 4) + ll]);
                *(ushort4*)&Vt[((size_t)(b * NH + h) * HD + (n << 4) + ll) * S_LEN + si] = o;
            }
        }
    }
}

// ---------------------------------------------------------------------------
// attn tile step (R6 exact, best measured): 32-row wave-tile, V frags
// DOUBLE-buffered in VGPRs, qn/mask prefetched one tile ahead, B-frags
// prefetched, packed-f32 transform; mask select folded into fma.
// Rejected by measurement: setprio (R12, -15%), (256,3) clamp (R8, spill),
// single-buffer V (R7, -3%), LDS-staged V (R14, -14%: reg-granule kept
// occupancy at 2 waves/SIMD while adding vmcnt waits on the PV path).
// ---------------------------------------------------------------------------
template<int CUR>
__device__ __forceinline__ void attn_tile32(
    int j0, int jn,
    const unsigned short* __restrict__ Qbase,
    const unsigned short* __restrict__ Vbase,
    const float* __restrict__ qnb, const float* __restrict__ mb,
    int ll, int lq,
    const bf16x8 (&aQ)[2][2],
    const f32x2 (&qni2)[2][2], const f32x2 (&keepi2)[2][2],
    const bf16x8& ones,
    f32x4 (&oacc)[2][4], f32x4 (&wacc)[2],
    bf16x8 (&nb0)[2], bf16x8 (&nb1)[2],
    bf16x8 (&vbuf)[2][4],
    float (&qnjv)[2][2], float (&kjm)[2][2],
    unsigned short (&Wt)[2][2][16][40])
{
    constexpr int PRV = CUR ^ 1;
    __builtin_amdgcn_wave_barrier();   // strip[PRV] writes (prev tile) before reads below
    // V-frags for current tile (consumed next tile)
#pragma unroll
    for (int m = 0; m < 4; m++)
        vbuf[CUR][m] = *(const bf16x8*)(Vbase + (size_t)((m << 4) + ll) * S_LEN + j0 + (lq << 3));
    // ---- gram(j0) with prefetched B-frags
    f32x4 s[2][2];
#pragma unroll
    for (int s2 = 0; s2 < 2; s2++)
#pragma unroll
        for (int n = 0; n < 2; n++) {
            f32x4 c = (f32x4){0.f, 0.f, 0.f, 0.f};
            c = __builtin_amdgcn_mfma_f32_16x16x32_bf16(aQ[s2][0], nb0[n], c, 0, 0, 0);
            c = __builtin_amdgcn_mfma_f32_16x16x32_bf16(aQ[s2][1], nb1[n], c, 0, 0, 0);
            s[s2][n] = c;
        }
    // ---- prefetch B-frags + qn/mask (next tile)
#pragma unroll
    for (int n = 0; n < 2; n++) {
        const unsigned short* bp = Qbase + (size_t)(jn + (n << 4) + ll) * HD + (lq << 3);
        nb0[n] = *(const bf16x8*)bp;
        nb1[n] = *(const bf16x8*)(bp + 32);
        int jc = jn + (n << 4) + ll;
        qnjv[PRV][n] = qnb[jc];
        kjm[PRV][n]  = (mb[jc] >= 0.f) ? 1.f : 0.f;
    }
    // ---- PV(previous tile)
#pragma unroll
    for (int s2 = 0; s2 < 2; s2++) {
        bf16x8 aP = *(const bf16x8*)&Wt[PRV][s2][ll][lq << 3];
#pragma unroll
        for (int m = 0; m < 4; m++)
            oacc[s2][m] = __builtin_amdgcn_mfma_f32_16x16x32_bf16(aP, vbuf[PRV][m], oacc[s2][m], 0, 0, 0);
        wacc[s2] = __builtin_amdgcn_mfma_f32_16x16x32_bf16(aP, ones, wacc[s2], 0, 0, 0);
    }
    // ---- transform(current) -> strip[CUR], packed f32 pairs over r
#pragma unroll
    for (int s2 = 0; s2 < 2; s2++)
#pragma unroll
        for (int n = 0; n < 2; n++) {
            const f32x2 qv = (f32x2)(qnjv[CUR][n]);
            const f32x2 kj = (f32x2)(kjm[CUR][n]);
#pragma unroll
            for (int pr = 0; pr < 2; pr++) {
                f32x2 sp = { s[s2][n][2*pr], s[s2][n][2*pr + 1] };
                f32x2 d2 = __builtin_elementwise_fma(sp, (f32x2)(-2.f), qni2[s2][pr] + qv);
                d2 = __builtin_elementwise_max(d2, (f32x2)(1e-12f));
                f32x2 dist = { __builtin_amdgcn_sqrtf(d2.x), __builtin_amdgcn_sqrtf(d2.y) };
                f32x2 km = keepi2[s2][pr] * kj;
                f32x2 x  = __builtin_elementwise_fma(km, dist + (f32x2)(-2.f), (f32x2)(3.f));
                f32x2 x2 = x * x;
                f32x2 x4 = x2 * x2;
                f32x2 x6 = x4 * x2;
                f32x2 x7 = x6 * x;
                f32x2 p  = { rsq_f32(x7.x), rsq_f32(x7.y) };   // (1+d)^-3.5
                f32x2 wv = __builtin_elementwise_fma(
                    __builtin_elementwise_fma(
                        __builtin_elementwise_fma(
                            __builtin_elementwise_fma((f32x2)(0.041666668f), p, (f32x2)(0.16666667f)),
                            p, (f32x2)(0.5f)),
                        p, (f32x2)(1.0f)),
                    p, (f32x2)(1.0f));
                union { float f; unsigned int u; } c0, c1;
                c0.f = wv.x; c1.f = wv.y;
                Wt[CUR][s2][(lq << 2) + 2*pr    ][(n << 4) + ll] = (unsigned short)((c0.u + 0x8000u) >> 16);
                Wt[CUR][s2][(lq << 2) + 2*pr + 1][(n << 4) + ll] = (unsigned short)((c1.u + 0x8000u) >> 16);
            }
        }
}

// ---------------------------------------------------------------------------
// Kernel 2: MFMA distance attention — R6/R13 structure (best measured:
// 107.4us, confirmed x3).  4 waves/block, 16-tile j-chunks, V double-
// buffered in VGPRs, qn/mask prefetch, NO clamp, NO setprio.
// Cross-wave reduction: 3-stage LDS tree; scratch aliases Wt (20480 B).
// Grid LINEAR, id = ib*24 + bh (24 % 8 == 0 keeps one (b,h) per XCD).
// ---------------------------------------------------------------------------
__global__ __launch_bounds__(256) void attn_kernel(
    const unsigned short* __restrict__ Qb, const unsigned short* __restrict__ Vt,
    const float* __restrict__ qn, const float* __restrict__ mask,
    unsigned short* __restrict__ AObf)
{
    __shared__ __align__(16) unsigned short Wt[4][2][2][16][40];  // [wave][buf][sub][i][j+pad] = 20480 B

    const int t  = threadIdx.x;
    const int w  = t >> 6;                     // wave id 0..3
    const int l  = t & 63;
    const int ll = l & 15;
    const int lq = l >> 4;
    const int id = blockIdx.x;
    const int ib = id / 24;
    const int bh = id - ib * 24;
    const int b  = bh / NH;
    const int h  = bh - b * NH;
    const int iw = ib << 5;                    // 32 i-rows (shared by all 4 waves)

    const unsigned short* Qbase = Qb + ((size_t)bh << 17);
    const unsigned short* Vbase = Vt + ((size_t)bh << 17);
    const float* qnb = qn + (bh << 11);
    const float* mb  = mask + (b << 11);

    unsigned short (&Wtw)[2][2][16][40] = Wt[w];

    // this wave's j-chunk: tiles [tbase, tbase+16), j in [jb, jb+512)
    const int tbase = w << 4;
    const int jb    = tbase << 5;

    // A-frags for both 16-row sub-tiles, held all loop
    bf16x8 aQ[2][2];
#pragma unroll
    for (int s2 = 0; s2 < 2; s2++) {
        const unsigned short* qp = Qbase + (size_t)(iw + (s2 << 4) + ll) * HD + (lq << 3);
        aQ[s2][0] = *(const bf16x8*)qp;
        aQ[s2][1] = *(const bf16x8*)(qp + 32);
    }

    f32x2 qni2[2][2], keepi2[2][2];
#pragma unroll
    for (int s2 = 0; s2 < 2; s2++)
#pragma unroll
        for (int pr = 0; pr < 2; pr++) {
            int r0 = iw + (s2 << 4) + (lq << 2) + 2*pr;
            qni2[s2][pr]   = (f32x2){ qnb[r0], qnb[r0 + 1] };
            keepi2[s2][pr] = (f32x2){ (mb[r0] >= 0.f) ? 1.f : 0.f,
                                      (mb[r0 + 1] >= 0.f) ? 1.f : 0.f };
        }

    bf16x8 ones;
#pragma unroll
    for (int i = 0; i < 8; i++) ones[i] = (short)0x3F80;   // bf16 1.0

    f32x4 oacc[2][4];
#pragma unroll
    for (int s2 = 0; s2 < 2; s2++)
#pragma unroll
        for (int m = 0; m < 4; m++) oacc[s2][m] = (f32x4){0.f, 0.f, 0.f, 0.f};
    f32x4 wacc[2];
    wacc[0] = (f32x4){0.f, 0.f, 0.f, 0.f};
    wacc[1] = (f32x4){0.f, 0.f, 0.f, 0.f};

    // gram B-frags + qn/mask for first tile of chunk
    bf16x8 nb0[2], nb1[2];
    float qnjv[2][2], kjm[2][2];
#pragma unroll
    for (int n = 0; n < 2; n++) {
        const unsigned short* bp = Qbase + (size_t)(jb + (n << 4) + ll) * HD + (lq << 3);
        nb0[n] = *(const bf16x8*)bp;
        nb1[n] = *(const bf16x8*)(bp + 32);
        int jc = jb + (n << 4) + ll;
        qnjv[0][n] = qnb[jc];
        kjm[0][n]  = (mb[jc] >= 0.f) ? 1.f : 0.f;
    }
    bf16x8 vbuf[2][4];

    // ---- peeled tile tbase: V -> vbuf[0], scores -> strip[0],
    //      prefetch B/qn/mask for tile tbase+1
    {
#pragma unroll
        for (int m = 0; m < 4; m++)
            vbuf[0][m] = *(const bf16x8*)(Vbase + (size_t)((m << 4) + ll) * S_LEN + jb + (lq << 3));
        f32x4 s[2][2];
#pragma unroll
        for (int s2 = 0; s2 < 2; s2++)
#pragma unroll
            for (int n = 0; n < 2; n++) {
                f32x4 c = (f32x4){0.f, 0.f, 0.f, 0.f};
                c = __builtin_amdgcn_mfma_f32_16x16x32_bf16(aQ[s2][0], nb0[n], c, 0, 0, 0);
                c = __builtin_amdgcn_mfma_f32_16x16x32_bf16(aQ[s2][1], nb1[n], c, 0, 0, 0);
                s[s2][n] = c;
            }
#pragma unroll
        for (int n = 0; n < 2; n++) {
            const unsigned short* bp = Qbase + (size_t)(jb + 32 + (n << 4) + ll) * HD + (lq << 3);
            nb0[n] = *(const bf16x8*)bp;
            nb1[n] = *(const bf16x8*)(bp + 32);
            int jc = jb + 32 + (n << 4) + ll;
            qnjv[1][n] = qnb[jc];
            kjm[1][n]  = (mb[jc] >= 0.f) ? 1.f : 0.f;
        }
#pragma unroll
        for (int s2 = 0; s2 < 2; s2++)
#pragma unroll
            for (int n = 0; n < 2; n++) {
                const f32x2 qv = (f32x2)(qnjv[0][n]);
                const f32x2 kj = (f32x2)(kjm[0][n]);
#pragma unroll
                for (int pr = 0; pr < 2; pr++) {
                    f32x2 sp = { s[s2][n][2*pr], s[s2][n][2*pr + 1] };
                    f32x2 d2 = __builtin_elementwise_fma(sp, (f32x2)(-2.f), qni2[s2][pr] + qv);
                    d2 = __builtin_elementwise_max(d2, (f32x2)(1e-12f));
                    f32x2 dist = { __builtin_amdgcn_sqrtf(d2.x), __builtin_amdgcn_sqrtf(d2.y) };
                    f32x2 km = keepi2[s2][pr] * kj;
                    f32x2 x  = __builtin_elementwise_fma(km, dist + (f32x2)(-2.f), (f32x2)(3.f));
                    f32x2 x2 = x * x;
                    f32x2 x4 = x2 * x2;
                    f32x2 x6 = x4 * x2;
                    f32x2 x7 = x6 * x;
                    f32x2 p  = { rsq_f32(x7.x), rsq_f32(x7.y) };
                    f32x2 wv = __builtin_elementwise_fma(
                        __builtin_elementwise_fma(
                            __builtin_elementwise_fma(
                                __builtin_elementwise_fma((f32x2)(0.041666668f), p, (f32x2)(0.16666667f)),
                                p, (f32x2)(0.5f)),
                            p, (f32x2)(1.0f)),
                        p, (f32x2)(1.0f));
                    union { float f; unsigned int u; } c0, c1;
                    c0.f = wv.x; c1.f = wv.y;
                    Wtw[0][s2][(lq << 2) + 2*pr    ][(n << 4) + ll] = (unsigned short)((c0.u + 0x8000u) >> 16);
                    Wtw[0][s2][(lq << 2) + 2*pr + 1][(n << 4) + ll] = (unsigned short)((c1.u + 0x8000u) >> 16);
                }
            }
    }

    // ---- tiles tbase+1 .. tbase+14 as 7 template-unrolled pairs
    //      (odd tile CUR=1, even tile CUR=0)
    for (int tt = tbase + 1; tt <= tbase + 13; tt += 2) {
        attn_tile32<1>(tt << 5, (tt + 1) << 5, Qbase, Vbase, qnb, mb, ll, lq,
                       aQ, qni2, keepi2, ones, oacc, wacc, nb0, nb1, vbuf, qnjv, kjm, Wtw);
        attn_tile32<0>((tt + 1) << 5, (tt + 2) << 5, Qbase, Vbase, qnb, mb, ll, lq,
                       aQ, qni2, keepi2, ones, oacc, wacc, nb0, nb1, vbuf, qnjv, kjm, Wtw);
    }
    // ---- tile tbase+15 (CUR=1; next-prefetch wraps to j=0, harmless)
    attn_tile32<1>((tbase + 15) << 5, 0, Qbase, Vbase, qnb, mb, ll, lq,
                   aQ, qni2, keepi2, ones, oacc, wacc, nb0, nb1, vbuf, qnjv, kjm, Wtw);

    // ---- drain: PV(last tile) from strip[1]/vbuf[1]
    __builtin_amdgcn_wave_barrier();
#pragma unroll
    for (int s2 = 0; s2 < 2; s2++) {
        bf16x8 aP = *(const bf16x8*)&Wtw[1][s2][ll][lq << 3];
#pragma unroll
        for (int m = 0; m < 4; m++)
            oacc[s2][m] = __builtin_amdgcn_mfma_f32_16x16x32_bf16(aP, vbuf[1][m], oacc[s2][m], 0, 0, 0);
        wacc[s2] = __builtin_amdgcn_mfma_f32_16x16x32_bf16(aP, ones, wacc[s2], 0, 0, 0);
    }

    // ---- cross-wave reduction of partials (40 f32/lane), LDS aliases Wt.
    //      Layout lane-major: red[slot*128 + idx], conflict-free.
    float* red = (float*)Wt;
    __syncthreads();
    if (w >= 2) {
        float* p = red + (((w - 2) << 6) + l);
#pragma unroll
        for (int s2 = 0; s2 < 2; s2++)
#pragma unroll
            for (int m = 0; m < 4; m++)
#pragma unroll
                for (int r = 0; r < 4; r++)
                    p[((((s2 << 2) + m) << 2) + r) * 128] = oacc[s2][m][r];
#pragma unroll
        for (int s2 = 0; s2 < 2; s2++)
#pragma unroll
            for (int r = 0; r < 4; r++)
                p[(32 + (s2 << 2) + r) * 128] = wacc[s2][r];
    }
    __syncthreads();
    if (w < 2) {
        float* p = red + ((w << 6) + l);
#pragma unroll
        for (int s2 = 0; s2 < 2; s2++)
#pragma unroll
            for (int m = 0; m < 4; m++)
#pragma unroll
                for (int r = 0; r < 4; r++)
                    oacc[s2][m][r] += p[((((s2 << 2) + m) << 2) + r) * 128];
#pragma unroll
        for (int s2 = 0; s2 < 2; s2++)
#pragma unroll
            for (int r = 0; r < 4; r++)
                wacc[s2][r] += p[(32 + (s2 << 2) + r) * 128];
    }
    __syncthreads();
    if (w == 1) {
        float* p = red + l;
#pragma unroll
        for (int s2 = 0; s2 < 2; s2++)
#pragma unroll
            for (int m = 0; m < 4; m++)
#pragma unroll
                for (int r = 0; r < 4; r++)
                    p[((((s2 << 2) + m) << 2) + r) * 128] = oacc[s2][m][r];
#pragma unroll
        for (int s2 = 0; s2 < 2; s2++)
#pragma unroll
            for (int r = 0; r < 4; r++)
                p[(32 + (s2 << 2) + r) * 128] = wacc[s2][r];
    }
    __syncthreads();
    if (w == 0) {
        float* p = red + l;
#pragma unroll
        for (int s2 = 0; s2 < 2; s2++)
#pragma unroll
            for (int m = 0; m < 4; m++)
#pragma unroll
                for (int r = 0; r < 4; r++)
                    oacc[s2][m][r] += p[((((s2 << 2) + m) << 2) + r) * 128];
#pragma unroll
        for (int s2 = 0; s2 < 2; s2++)
#pragma unroll
            for (int r = 0; r < 4; r++)
                wacc[s2][r] += p[(32 + (s2 << 2) + r) * 128];

        // ---- epilogue (wave 0 holds full sums): normalize + store 32 rows
#pragma unroll
        for (int s2 = 0; s2 < 2; s2++)
#pragma unroll
            for (int r = 0; r < 4; r++) {
                float inv = 1.0f / wacc[s2][r];
                const int row = iw + (s2 << 4) + (lq << 2) + r;
                unsigned short* dst = AObf + (size_t)((b << 11) + row) * EDIM + (h << 6);
#pragma unroll
                for (int m = 0; m < 4; m++)
                    dst[(m << 4) + ll] = f2bf(oacc[s2][m][r] * inv);
            }
    }
}

// ---------------------------------------------------------------------------
// Kernel 3a: out-projection bf16 MFMA GEMM + bias + residual (fp32 out).
// R10/R13 config (best measured): 64x64 tiles, 4 waves (2x2), wave-tile
// 32x32, grid (12, 64) = 768 blocks.  gload16 + swz4 staging, double-
// buffered.  LDS 16 KB.
// ---------------------------------------------------------------------------
__global__ __launch_bounds__(256) void oproj_gemm(
    const unsigned short* __restrict__ AObf, const unsigned short* __restrict__ Wob,
    const float* __restrict__ bo, const float* __restrict__ hs,
    float* __restrict__ TMP)
{
    __shared__ __align__(16) unsigned short As[2][64][32];
    __shared__ __align__(16) unsigned short Bs[2][64][32];

    const int t  = threadIdx.x;
    const int m0 = blockIdx.y << 6;
    const int c0 = blockIdx.x << 6;

    const int w  = t >> 6;
    const int l  = t & 63;
    const int ll = l & 15;
    const int lq = l >> 4;
    const int wx = w & 1;
    const int wy = w >> 1;

    const int srow = (w << 4) + (l >> 2);             // rows 0..63
    const unsigned short* aSrc = AObf + (size_t)(m0 + srow) * EDIM + (((l & 3) ^ swz4(srow)) << 3);
    const unsigned short* bSrc = Wob  + (size_t)(c0 + srow) * EDIM + (((l & 3) ^ swz4(srow)) << 3);

    f32x4 acc[2][2];
#pragma unroll
    for (int m = 0; m < 2; m++)
#pragma unroll
        for (int n = 0; n < 2; n++) acc[m][n] = (f32x4){0.f, 0.f, 0.f, 0.f};

    gload16(aSrc, &As[0][w << 4][0]);
    gload16(bSrc, &Bs[0][w << 4][0]);
    __syncthreads();

    int cur = 0;
    for (int k0 = 0; k0 < EDIM; k0 += 32) {
        if (k0 + 32 < EDIM) {
            gload16(aSrc + k0 + 32, &As[cur ^ 1][w << 4][0]);
            gload16(bSrc + k0 + 32, &Bs[cur ^ 1][w << 4][0]);
        }
        bf16x8 aF[2], bF[2];
#pragma unroll
        for (int m = 0; m < 2; m++) {
            const int row = (wy << 5) + (m << 4) + ll;
            aF[m] = *(const bf16x8*)&As[cur][row][(lq ^ swz4(row)) << 3];
        }
#pragma unroll
        for (int n = 0; n < 2; n++) {
            const int row = (wx << 5) + (n << 4) + ll;
            bF[n] = *(const bf16x8*)&Bs[cur][row][(lq ^ swz4(row)) << 3];
        }
#pragma unroll
        for (int m = 0; m < 2; m++)
#pragma unroll
            for (int n = 0; n < 2; n++)
                acc[m][n] = __builtin_amdgcn_mfma_f32_16x16x32_bf16(aF[m], bF[n], acc[m][n], 0, 0, 0);
        __syncthreads();
        cur ^= 1;
    }

#pragma unroll
    for (int m = 0; m < 2; m++) {
#pragma unroll
        for (int r = 0; r < 4; r++) {
            const int row = m0 + (wy << 5) + (m << 4) + (lq << 2) + r;
#pragma unroll
            for (int n = 0; n < 2; n++) {
                const int col = c0 + (wx << 5) + (n << 4) + ll;
                TMP[(size_t)row * EDIM + col] =
                    acc[m][n][r] + bo[col] + hs[(size_t)row * EDIM + col];
            }
        }
    }
}

// ---------------------------------------------------------------------------
// Kernel 3b: LayerNorm -> f32 output.  grid 4096, block 256.
// ---------------------------------------------------------------------------
__global__ __launch_bounds__(256) void ln_kernel(
    const float* __restrict__ X, const float* __restrict__ g,
    const float* __restrict__ be, float* __restrict__ out)
{
    const int row = blockIdx.x;
    const int t = threadIdx.x;
    const float* x = X + (size_t)row * EDIM;

    float s = 0.f, sq = 0.f;
#pragma unroll
    for (int c = t; c < EDIM; c += 256) {
        float v = x[c];
        s += v; sq += v * v;
    }
#pragma unroll
    for (int m = 1; m < 64; m <<= 1) {
        s  += __shfl_xor(s, m);
        sq += __shfl_xor(sq, m);
    }
    __shared__ float ss[4], ssq[4];
    const int w = t >> 6;
    if ((t & 63) == 0) { ss[w] = s; ssq[w] = sq; }
    __syncthreads();
    s  = ss[0] + ss[1] + ss[2] + ss[3];
    sq = ssq[0] + ssq[1] + ssq[2] + ssq[3];
    const float mu  = s * (1.f / EDIM);
    const float var = sq * (1.f / EDIM) - mu * mu;
    const float rstd = 1.0f / sqrtf(var + 1e-12f);

#pragma unroll
    for (int c = t; c < EDIM; c += 256) {
        out[(size_t)row * EDIM + c] = (x[c] - mu) * rstd * g[c] + be[c];
    }
}

// ---------------------------------------------------------------------------
extern "C" void kernel_launch(void* const* d_in, const int* in_sizes, int n_in,
                              void* d_out, int out_size, void* d_ws, size_t ws_size,
                              hipStream_t stream) {
    const float* hs   = (const float*)d_in[0];
    const float* mask = (const float*)d_in[1];
    const float* Wq   = (const float*)d_in[2];
    const float* bq   = (const float*)d_in[3];
    const float* Wv   = (const float*)d_in[4];
    const float* bv   = (const float*)d_in[5];
    const float* Wo   = (const float*)d_in[6];
    const float* bo   = (const float*)d_in[7];
    const float* g    = (const float*)d_in[8];
    const float* be   = (const float*)d_in[9];

    char* w8 = (char*)d_ws;
    unsigned short* Qb   = (unsigned short*)(w8);               //  6,291,456 B
    unsigned short* Vt   = (unsigned short*)(w8 +  6291456);    //  6,291,456 B
    float*          qn   = (float*)        (w8 + 12582912);     //    196,608 B
    unsigned short* AObf = (unsigned short*)(w8 + 12779520);    //  6,291,456 B
    unsigned short* hsb  = (unsigned short*)(w8 + 19070976);    //  6,291,456 B
    unsigned short* Wqvb = (unsigned short*)(w8 + 25362432);    //  2,359,296 B
    unsigned short* Wob  = (unsigned short*)(w8 + 27721728);    //  1,179,648 B
    float*          TMP  = (float*)(w8);                        // alias Qb+Vt (dead)

    precast_kernel<<<dim3(4800),    256, 0, stream>>>(hs, Wq, Wv, Wo, hsb, Wqvb, Wob);
    qv_gemm       <<<dim3(12, 64),  256, 0, stream>>>(hsb, Wqvb, bq, bv, Qb, Vt, qn);
    attn_kernel   <<<dim3(1536),    256, 0, stream>>>(Qb, Vt, qn, mask, AObf);
    oproj_gemm    <<<dim3(12, 64),  256, 0, stream>>>(AObf, Wob, bo, hs, TMP);
    ln_kernel     <<<dim3(4096),    256, 0, stream>>>(TMP, g, be, (float*)d_out);
}